// Round 16
// baseline (165.456 us; speedup 1.0000x reference)
//
#include <hip/hip_runtime.h>

typedef unsigned short u16;
typedef unsigned int   u32;
typedef __bf16 bf16x8 __attribute__((ext_vector_type(8)));
typedef float  f32x4  __attribute__((ext_vector_type(4)));
typedef float  f32x16 __attribute__((ext_vector_type(16)));
typedef u32    u32x4  __attribute__((ext_vector_type(4)));

__device__ __forceinline__ u16 f2bf(float f) {
  u32 u = __builtin_bit_cast(u32, f);
  u += 0x7fffu + ((u >> 16) & 1u);   // RNE
  return (u16)(u >> 16);
}

#define GLOAD_LDS16(gptr, lptr)                                              \
  __builtin_amdgcn_global_load_lds(                                          \
      (const __attribute__((address_space(1))) void*)(gptr),                 \
      (__attribute__((address_space(3))) void*)(lptr), 16, 0, 0)

#define QK_FOLD 0.18033688011112042f   // 0.125 * log2(e): softmax in base-2

// ---------------------------------------------------------------- merged prep
__global__ __launch_bounds__(256) void prep_kernel(const float* __restrict__ x,
                                                   u16* __restrict__ xb,
                                                   const float* __restrict__ Wq,
                                                   u16* __restrict__ Wqt,
                                                   const float* __restrict__ Wp,
                                                   u16* __restrict__ Wpt,
                                                   float* __restrict__ cost,
                                                   float* __restrict__ sint) {
  __shared__ float tile[32][33];
  const int bid = blockIdx.x;
  if (bid < 4096) {
    const int i = bid * 256 + threadIdx.x;          // 1048576 = 4096*256 exact
    const float4 v = ((const float4*)x)[i];
    uint2 o;
    o.x = (u32)f2bf(v.x) | ((u32)f2bf(v.y) << 16);
    o.y = (u32)f2bf(v.z) | ((u32)f2bf(v.w) << 16);
    ((uint2*)xb)[i] = o;
  } else if (bid < 8192) {
    const bool isq = bid < 7168;
    const float* W = isq ? Wq : Wp;
    u16* Wt = isq ? Wqt : Wpt;
    const int t = isq ? (bid - 4096) : (bid - 7168);
    const int ntiles = isq ? 96 : 32;
    const int N = isq ? 3072 : 1024;
    const int k0 = (t / ntiles) * 32, n0 = (t % ntiles) * 32;
    const int tx = threadIdx.x & 31, ty = threadIdx.x >> 5;   // 32 x 8
#pragma unroll
    for (int i = 0; i < 32; i += 8)
      tile[ty + i][tx] = W[(size_t)(k0 + ty + i) * N + n0 + tx];
    __syncthreads();
#pragma unroll
    for (int i = 0; i < 32; i += 8)
      Wt[(size_t)(n0 + ty + i) * 1024 + k0 + tx] = f2bf(tile[tx][ty + i]);
  } else {
    const int idx = (bid - 8192) * 256 + threadIdx.x;   // 65536 = 2048 * 32
    const int s = idx >> 5, i = idx & 31;
    float inv = exp2f(-13.287712379549449f * (float)i * (1.0f / 32.0f));  // 10000^(-i/32)
    float sn, cs;
    sincosf((float)s * inv, &sn, &cs);
    cost[idx] = cs;
    sint[idx] = sn;
  }
}

// ---------------------------------------------------------------- QKV GEMM fused
__global__ __launch_bounds__(256) void gemm_qkv_rope_kernel(const u16* __restrict__ A,
                                                            const u16* __restrict__ Bt,
                                                            const float* __restrict__ bias,
                                                            const float* __restrict__ cost,
                                                            const float* __restrict__ sint,
                                                            u16* __restrict__ qb,
                                                            u16* __restrict__ kb,
                                                            u16* __restrict__ vt) {
  __shared__ u16 As[128][64];
  __shared__ u16 Bs[128][64];
  const int bm = blockIdx.y, bn = blockIdx.x;
  const int tid = threadIdx.x;
  const int wave = tid >> 6, lane = tid & 63;
  const int wr = wave >> 1, wc = wave & 1;
  const int l15 = lane & 15, lhi = lane >> 4;
  f32x4 acc[4][4] = {};
  const int K = 1024;

  const size_t arow0 = (size_t)bm * 128, brow0 = (size_t)bn * 128;
  const int srow_in = lane >> 3;
  const int sslot   = (lane & 7) ^ srow_in;

  for (int k0 = 0; k0 < K; k0 += 64) {
#pragma unroll
    for (int i = 0; i < 4; i++) {
      const int r = wave * 32 + i * 8 + srow_in;
      GLOAD_LDS16(A  + (arow0 + r) * K + k0 + sslot * 8, &As[wave * 32 + i * 8][0]);
      GLOAD_LDS16(Bt + (brow0 + r) * K + k0 + sslot * 8, &Bs[wave * 32 + i * 8][0]);
    }
    __syncthreads();

    bf16x8 af[4][2], bfr[4][2];
#pragma unroll
    for (int m = 0; m < 4; m++) {
      const int r = wr * 64 + m * 16 + l15;
#pragma unroll
      for (int kk = 0; kk < 2; kk++)
        af[m][kk] = *(const bf16x8*)(&As[0][0] + r * 64 + (((kk * 4 + lhi) ^ (r & 7)) * 8));
    }
#pragma unroll
    for (int n = 0; n < 4; n++) {
      const int r = wc * 64 + n * 16 + l15;
#pragma unroll
      for (int kk = 0; kk < 2; kk++)
        bfr[n][kk] = *(const bf16x8*)(&Bs[0][0] + r * 64 + (((kk * 4 + lhi) ^ (r & 7)) * 8));
    }
#pragma unroll
    for (int m = 0; m < 4; m++)
#pragma unroll
      for (int n = 0; n < 4; n++) {
        acc[m][n] = __builtin_amdgcn_mfma_f32_16x16x32_bf16(af[m][0], bfr[n][0], acc[m][n], 0, 0, 0);
        acc[m][n] = __builtin_amdgcn_mfma_f32_16x16x32_bf16(af[m][1], bfr[n][1], acc[m][n], 0, 0, 0);
      }
    __syncthreads();
  }

  float bv[4];
#pragma unroll
  for (int n = 0; n < 4; n++) bv[n] = bias[bn * 128 + wc * 64 + n * 16 + l15];

  if (bn < 16) {   // ---- q or k: bias + RoPE ----
    const bool isq = bn < 8;
    u16* dst = isq ? qb : kb;
    const int hcol = bn * 2 + wc - (isq ? 0 : 16);   // head 0..15
    const float fold = isq ? QK_FOLD : 1.0f;
#pragma unroll
    for (int m = 0; m < 4; m++)
#pragma unroll
      for (int r = 0; r < 4; r++) {
        const int row = bm * 128 + wr * 64 + m * 16 + lhi * 4 + r;
        const int b = row >> 11, s = row & 2047;
        const float cs0 = cost[s * 32 + l15],      sn0 = sint[s * 32 + l15];
        const float cs1 = cost[s * 32 + 16 + l15], sn1 = sint[s * 32 + 16 + l15];
        const float q0 = acc[m][0][r] + bv[0], q1 = acc[m][2][r] + bv[2];
        const float q2 = acc[m][1][r] + bv[1], q3 = acc[m][3][r] + bv[3];
        u16* orow = dst + ((size_t)(b * 16 + hcol) * 2048 + s) * 64;
        orow[l15]      = f2bf((q0 * cs0 - q1 * sn0) * fold);
        orow[l15 + 32] = f2bf((q1 * cs0 + q0 * sn0) * fold);
        orow[l15 + 16] = f2bf((q2 * cs1 - q3 * sn1) * fold);
        orow[l15 + 48] = f2bf((q3 * cs1 + q2 * sn1) * fold);
      }
  } else {         // ---- v: bias + transpose to [bh][d][2048] ----
    const int hcol = bn * 2 + wc - 32;               // head 0..15
    const int b = bm >> 4;
#pragma unroll
    for (int n = 0; n < 4; n++) {
      const int d = n * 16 + l15;
      u16* dcol = vt + ((size_t)(b * 16 + hcol) * 64 + d) * 2048;
#pragma unroll
      for (int m = 0; m < 4; m++) {
        const int s = (bm * 128 + wr * 64 + m * 16 + lhi * 4) & 2047;
        uint2 w;
        w.x = (u32)f2bf(acc[m][n][0] + bv[n]) | ((u32)f2bf(acc[m][n][1] + bv[n]) << 16);
        w.y = (u32)f2bf(acc[m][n][2] + bv[n]) | ((u32)f2bf(acc[m][n][3] + bv[n]) << 16);
        *(uint2*)(dcol + s) = w;
      }
    }
  }
}

// ---------------------------------------------------------------- proj GEMM, 64x128 tile
__global__ __launch_bounds__(256) void gemm_bias_m64_kernel(const u16* __restrict__ A,
                                                            const u16* __restrict__ Bt,
                                                            const float* __restrict__ bias,
                                                            float* __restrict__ C,
                                                            int M, int N, int K) {
  __shared__ u16 As[64][64];
  __shared__ u16 Bs[128][64];
  const int bm = blockIdx.y, bn = blockIdx.x;
  const int tid = threadIdx.x;
  const int wave = tid >> 6, lane = tid & 63;
  const int wr = wave >> 1, wc = wave & 1;
  const int l15 = lane & 15, lhi = lane >> 4;
  f32x4 acc[2][4] = {};

  const size_t arow0 = (size_t)bm * 64, brow0 = (size_t)bn * 128;
  const int srow_in = lane >> 3;
  const int sslot   = (lane & 7) ^ srow_in;

  for (int k0 = 0; k0 < K; k0 += 64) {
#pragma unroll
    for (int i = 0; i < 2; i++) {   // A: 64 rows, 2 issues/wave
      const int r = wave * 16 + i * 8 + srow_in;
      GLOAD_LDS16(A + (arow0 + r) * K + k0 + sslot * 8, &As[wave * 16 + i * 8][0]);
    }
#pragma unroll
    for (int i = 0; i < 4; i++) {   // B: 128 rows, 4 issues/wave
      const int r = wave * 32 + i * 8 + srow_in;
      GLOAD_LDS16(Bt + (brow0 + r) * K + k0 + sslot * 8, &Bs[wave * 32 + i * 8][0]);
    }
    __syncthreads();

    bf16x8 af[2][2], bfr[4][2];
#pragma unroll
    for (int m = 0; m < 2; m++) {
      const int r = wr * 32 + m * 16 + l15;
#pragma unroll
      for (int kk = 0; kk < 2; kk++)
        af[m][kk] = *(const bf16x8*)(&As[0][0] + r * 64 + (((kk * 4 + lhi) ^ (r & 7)) * 8));
    }
#pragma unroll
    for (int n = 0; n < 4; n++) {
      const int r = wc * 64 + n * 16 + l15;
#pragma unroll
      for (int kk = 0; kk < 2; kk++)
        bfr[n][kk] = *(const bf16x8*)(&Bs[0][0] + r * 64 + (((kk * 4 + lhi) ^ (r & 7)) * 8));
    }
#pragma unroll
    for (int m = 0; m < 2; m++)
#pragma unroll
      for (int n = 0; n < 4; n++) {
        acc[m][n] = __builtin_amdgcn_mfma_f32_16x16x32_bf16(af[m][0], bfr[n][0], acc[m][n], 0, 0, 0);
        acc[m][n] = __builtin_amdgcn_mfma_f32_16x16x32_bf16(af[m][1], bfr[n][1], acc[m][n], 0, 0, 0);
      }
    __syncthreads();
  }
#pragma unroll
  for (int n = 0; n < 4; n++) {
    int col = bn * 128 + wc * 64 + n * 16 + l15;
    float bvv = bias[col];
#pragma unroll
    for (int m = 0; m < 2; m++)
#pragma unroll
      for (int r = 0; r < 4; r++) {
        int row = bm * 64 + wr * 32 + m * 16 + lhi * 4 + r;
        C[(size_t)row * N + col] = acc[m][n][r] + bvv;
      }
  }
}

// ---------------------------------------------------------------- flash attention (split-KV across BLOCKS)
// R13 per-block code bit-for-bit (validated 63.2us pipeline), but each block
// processes HALF the K-tiles (part in {0,1}) -> grid 1024 = 4 blocks/CU
// (LDS 4x32=128KB, VGPR 96 -> fits). Writes raw fp32 partials (O, m, l);
// flash_merge_kernel does the exact exp2 combine (math validated in R14).
// WATCH: WRITE_SIZE ~34MB expected (fp32 partials); spill would show as more.
__global__ __launch_bounds__(256) void flash_attn_kernel(const u16* __restrict__ qg,
                                                         const u16* __restrict__ kg,
                                                         const u16* __restrict__ vg,
                                                         float* __restrict__ opart,
                                                         float* __restrict__ ml) {
  __shared__ u16 Ks[2][64][64];
  __shared__ u16 Vs[2][64][64];
  const int hw = blockIdx.x;
  const int lb = (hw & 7) * 128 + (hw >> 3);     // XCD swizzle: 1024%8==0, bijective
  const int part = lb & 1, qt = (lb >> 1) & 15, bh = lb >> 5;
  const int tid = threadIdx.x, wave = tid >> 6, lane = tid & 63;
  const int l5 = lane & 31, hi = lane >> 5;

  const u16* qrow = qg + ((size_t)bh * 2048 + qt * 128 + wave * 32 + l5) * 64 + hi * 8;
  bf16x8 qf[4];
#pragma unroll
  for (int kc = 0; kc < 4; kc++) qf[kc] = *(const bf16x8*)(qrow + kc * 16);

  f32x16 o[2] = {};
  float m_run = -1e30f, l_run = 0.f;

  const u16* gK = kg + (size_t)bh * 2048 * 64;
  const u16* gV = vg + (size_t)bh * 64 * 2048;
  const int srow0 = tid >> 3, sc16 = tid & 7;
  const int kt0 = part * 16, kt1 = kt0 + 16;
  int4 kreg[2], vreg[2];

#pragma unroll
  for (int i = 0; i < 2; i++) {
    int r = srow0 + i * 32;
    kreg[i] = *(const int4*)(gK + ((size_t)kt0 * 64 + r) * 64 + sc16 * 8);
    vreg[i] = *(const int4*)(gV + (size_t)r * 2048 + kt0 * 64 + sc16 * 8);
  }
#pragma unroll
  for (int i = 0; i < 2; i++) {
    int r = srow0 + i * 32;
    int byo = r * 128 + ((sc16 * 16) ^ ((r & 7) << 4));
    *(int4*)((char*)&Ks[0][0][0] + byo) = kreg[i];
    *(int4*)((char*)&Vs[0][0][0] + byo) = vreg[i];
  }

  for (int kt = kt0; kt < kt1; kt++) {
    const int cur = kt & 1;
    __syncthreads();
    if (kt < kt1 - 1) {
#pragma unroll
      for (int i = 0; i < 2; i++) {
        int r = srow0 + i * 32;
        kreg[i] = *(const int4*)(gK + ((size_t)(kt + 1) * 64 + r) * 64 + sc16 * 8);
        vreg[i] = *(const int4*)(gV + (size_t)r * 2048 + (kt + 1) * 64 + sc16 * 8);
      }
    }
    const char* KsB = (const char*)&Ks[cur][0][0];
    const char* VsB = (const char*)&Vs[cur][0][0];

    f32x16 sf[2];
#pragma unroll
    for (int k32 = 0; k32 < 2; k32++) {
      int r = k32 * 32 + l5;
      const char* rowp = KsB + r * 128;
      int sw = (r & 7) << 4;
      f32x16 s = {};
#pragma unroll
      for (int kc = 0; kc < 4; kc++) {
        bf16x8 kf = *(const bf16x8*)(rowp + ((kc * 32 + hi * 16) ^ sw));
        s = __builtin_amdgcn_mfma_f32_32x32x16_bf16(kf, qf[kc], s, 0, 0, 0);
      }
      sf[k32] = s;
    }

    // ---- online softmax (base-2), chain max + defer-max (T13) ----
    float pmax = sf[0][0];
#pragma unroll
    for (int r = 1; r < 16; r++) pmax = fmaxf(pmax, sf[0][r]);
#pragma unroll
    for (int r = 0; r < 16; r++) pmax = fmaxf(pmax, sf[1][r]);
    pmax = fmaxf(pmax, __shfl_xor(pmax, 32));

    if (!__all(pmax - m_run <= 11.541560327111707f)) {
      float mnew = fmaxf(m_run, pmax);
      float alpha = __builtin_amdgcn_exp2f(m_run - mnew);
      m_run = mnew;
      l_run *= alpha;
#pragma unroll
      for (int dc = 0; dc < 2; dc++)
#pragma unroll
        for (int r = 0; r < 16; r++) o[dc][r] *= alpha;
    }
    float rs = 0.f;
#pragma unroll
    for (int k32 = 0; k32 < 2; k32++)
#pragma unroll
      for (int r = 0; r < 16; r++) {
        float p = __builtin_amdgcn_exp2f(sf[k32][r] - m_run);
        sf[k32][r] = p;
        rs += p;
      }
    rs += __shfl_xor(rs, 32);
    l_run += rs;

    bf16x8 pf[4];
#pragma unroll
    for (int k32 = 0; k32 < 2; k32++) {
      u32 u[8];
#pragma unroll
      for (int m = 0; m < 8; m++) {
        u32 w;
        asm("v_cvt_pk_bf16_f32 %0, %1, %2" : "=v"(w) : "v"(sf[k32][2 * m]), "v"(sf[k32][2 * m + 1]));
        u[m] = w;
      }
      asm("v_permlane32_swap_b32 %0, %1" : "+v"(u[0]), "+v"(u[2]));
      asm("v_permlane32_swap_b32 %0, %1" : "+v"(u[1]), "+v"(u[3]));
      asm("v_permlane32_swap_b32 %0, %1" : "+v"(u[4]), "+v"(u[6]));
      asm("v_permlane32_swap_b32 %0, %1" : "+v"(u[5]), "+v"(u[7]));
      u32x4 w0 = {u[0], u[1], u[2], u[3]};
      u32x4 w1 = {u[4], u[5], u[6], u[7]};
      pf[k32 * 2]     = __builtin_bit_cast(bf16x8, w0);
      pf[k32 * 2 + 1] = __builtin_bit_cast(bf16x8, w1);
    }

#pragma unroll
    for (int dc = 0; dc < 2; dc++) {
      int r = dc * 32 + l5;
      const char* rowp = VsB + r * 128;
      int sw = (r & 7) << 4;
#pragma unroll
      for (int kc = 0; kc < 4; kc++) {
        bf16x8 vf = *(const bf16x8*)(rowp + ((kc * 32 + hi * 16) ^ sw));
        o[dc] = __builtin_amdgcn_mfma_f32_32x32x16_bf16(vf, pf[kc], o[dc], 0, 0, 0);
      }
    }

    if (kt < kt1 - 1) {
#pragma unroll
      for (int i = 0; i < 2; i++) {
        int r = srow0 + i * 32;
        int byo = r * 128 + ((sc16 * 16) ^ ((r & 7) << 4));
        *(int4*)((char*)&Ks[cur ^ 1][0][0] + byo) = kreg[i];
        *(int4*)((char*)&Vs[cur ^ 1][0][0] + byo) = vreg[i];
      }
    }
  }

  // ---- write raw fp32 partial (O, m, l); merge kernel combines ----
  const int qglob = qt * 128 + wave * 32 + l5;
  const size_t idx = ((size_t)part * 32 + bh) * 2048 + qglob;
  float* orow = opart + idx * 64;
#pragma unroll
  for (int dc = 0; dc < 2; dc++)
#pragma unroll
    for (int m = 0; m < 4; m++) {
      const int d0 = dc * 32 + m * 8 + hi * 4;
      float4 w = {o[dc][4 * m + 0], o[dc][4 * m + 1],
                  o[dc][4 * m + 2], o[dc][4 * m + 3]};
      *(float4*)(orow + d0) = w;
    }
  if (hi == 0) {
    float2 p = {m_run, l_run};
    ((float2*)ml)[idx] = p;
  }
}

// ---------------------------------------------------------------- flash merge
// Exact combine of the two key-half partials (R14-validated math):
// M = max(m0,m1); O = (O0*2^(m0-M) + O1*2^(m1-M)) / (l0*2^(m0-M) + l1*2^(m1-M))
__global__ __launch_bounds__(256) void flash_merge_kernel(const float* __restrict__ opart,
                                                          const float* __restrict__ ml,
                                                          u16* __restrict__ og) {
  const int t = blockIdx.x * 256 + threadIdx.x;   // 262144 = 32*2048*4
  const int d0 = (t & 3) * 16;
  const int q  = (t >> 2) & 2047;
  const int bh = t >> 13;
  const int b = bh >> 4, h = bh & 15;
  const size_t idx = (size_t)bh * 2048 + q;
  const size_t pstride = (size_t)32 * 2048;       // part stride in (bh,q) units

  const float2 p0 = ((const float2*)ml)[idx];
  const float2 p1 = ((const float2*)ml)[pstride + idx];
  const float M = fmaxf(p0.x, p1.x);
  const float a0 = __builtin_amdgcn_exp2f(p0.x - M);
  const float a1 = __builtin_amdgcn_exp2f(p1.x - M);
  const float rinv = 1.0f / (p0.y * a0 + p1.y * a1);

  const float* o0 = opart + idx * 64 + d0;
  const float* o1 = opart + (pstride + idx) * 64 + d0;
  u32 w[8];
#pragma unroll
  for (int j = 0; j < 4; j++) {
    const float4 x0 = *(const float4*)(o0 + j * 4);
    const float4 x1 = *(const float4*)(o1 + j * 4);
    const float v0 = (x0.x * a0 + x1.x * a1) * rinv;
    const float v1 = (x0.y * a0 + x1.y * a1) * rinv;
    const float v2 = (x0.z * a0 + x1.z * a1) * rinv;
    const float v3 = (x0.w * a0 + x1.w * a1) * rinv;
    w[j * 2]     = (u32)f2bf(v0) | ((u32)f2bf(v1) << 16);
    w[j * 2 + 1] = (u32)f2bf(v2) | ((u32)f2bf(v3) << 16);
  }
  u16* orow = og + ((size_t)b * 2048 + q) * 1024 + h * 64 + d0;
  u32x4 wa = {w[0], w[1], w[2], w[3]};
  u32x4 wb = {w[4], w[5], w[6], w[7]};
  *(u32x4*)(orow) = wa;
  *(u32x4*)(orow + 8) = wb;
}

// ---------------------------------------------------------------- launch
extern "C" void kernel_launch(void* const* d_in, const int* in_sizes, int n_in,
                              void* d_out, int out_size, void* d_ws, size_t ws_size,
                              hipStream_t stream) {
  const float* x     = (const float*)d_in[0];
  const float* Wqkv  = (const float*)d_in[1];
  const float* bqkv  = (const float*)d_in[2];
  const float* Wproj = (const float*)d_in[3];
  const float* bproj = (const float*)d_in[4];
  float* out = (float*)d_out;

  // workspace layout (<= 96 MB)
  char* ws = (char*)d_ws;
  u16*   xb    = (u16*)ws;                                   // 8 MB  [4096][1024]
  u16*   wqkvt = xb + (size_t)4096 * 1024;                   // 6 MB  [3072][1024]
  u16*   wprot = wqkvt + (size_t)3072 * 1024;                // 2 MB  [1024][1024]
  float* cost  = (float*)(ws + (size_t)16 * 1024 * 1024);    // 256 KB [2048][32]
  float* sint  = cost + 2048 * 32;                           // 256 KB
  float* opart = (float*)(ws + (size_t)24 * 1024 * 1024);    // 32 MB [2][32][2048][64] f32
  float* mlbuf = (float*)(ws + (size_t)56 * 1024 * 1024);    // 1 MB  [2][32][2048][2] f32
  u16*   qb2   = (u16*)(ws + (size_t)64 * 1024 * 1024);      // 8 MB  [32][2048][64]
  u16*   kb2   = (u16*)(ws + (size_t)72 * 1024 * 1024);      // 8 MB
  u16*   vtw   = (u16*)(ws + (size_t)80 * 1024 * 1024);      // 8 MB  [32][64][2048]
  u16*   obw   = (u16*)(ws + (size_t)88 * 1024 * 1024);      // 8 MB  [4096][1024]

  prep_kernel<<<dim3(8448), dim3(256), 0, stream>>>(x, xb, Wqkv, wqkvt, Wproj, wprot, cost, sint);
  gemm_qkv_rope_kernel<<<dim3(24, 32), dim3(256), 0, stream>>>(xb, wqkvt, bqkv, cost, sint,
                                                               qb2, kb2, vtw);
  flash_attn_kernel<<<dim3(1024), dim3(256), 0, stream>>>(qb2, kb2, vtw, opart, mlbuf);
  flash_merge_kernel<<<dim3(1024), dim3(256), 0, stream>>>(opart, mlbuf, obw);
  gemm_bias_m64_kernel<<<dim3(8, 64), dim3(256), 0, stream>>>(obw, wprot, bproj, out, 4096, 1024, 1024);
}

// Round 17
// 128.179 us; speedup vs baseline: 1.2908x; 1.2908x over previous
//
#include <hip/hip_runtime.h>

typedef unsigned short u16;
typedef unsigned int   u32;
typedef __bf16 bf16x8 __attribute__((ext_vector_type(8)));
typedef float  f32x4  __attribute__((ext_vector_type(4)));
typedef float  f32x16 __attribute__((ext_vector_type(16)));
typedef u32    u32x4  __attribute__((ext_vector_type(4)));

__device__ __forceinline__ u16 f2bf(float f) {
  u32 u = __builtin_bit_cast(u32, f);
  u += 0x7fffu + ((u >> 16) & 1u);   // RNE
  return (u16)(u >> 16);
}

#define GLOAD_LDS16(gptr, lptr)                                              \
  __builtin_amdgcn_global_load_lds(                                          \
      (const __attribute__((address_space(1))) void*)(gptr),                 \
      (__attribute__((address_space(3))) void*)(lptr), 16, 0, 0)

#define QK_FOLD 0.18033688011112042f   // 0.125 * log2(e): softmax in base-2

// ---------------------------------------------------------------- merged prep
__global__ __launch_bounds__(256) void prep_kernel(const float* __restrict__ x,
                                                   u16* __restrict__ xb,
                                                   const float* __restrict__ Wq,
                                                   u16* __restrict__ Wqt,
                                                   const float* __restrict__ Wp,
                                                   u16* __restrict__ Wpt,
                                                   float* __restrict__ cost,
                                                   float* __restrict__ sint) {
  __shared__ float tile[32][33];
  const int bid = blockIdx.x;
  if (bid < 4096) {
    const int i = bid * 256 + threadIdx.x;          // 1048576 = 4096*256 exact
    const float4 v = ((const float4*)x)[i];
    uint2 o;
    o.x = (u32)f2bf(v.x) | ((u32)f2bf(v.y) << 16);
    o.y = (u32)f2bf(v.z) | ((u32)f2bf(v.w) << 16);
    ((uint2*)xb)[i] = o;
  } else if (bid < 8192) {
    const bool isq = bid < 7168;
    const float* W = isq ? Wq : Wp;
    u16* Wt = isq ? Wqt : Wpt;
    const int t = isq ? (bid - 4096) : (bid - 7168);
    const int ntiles = isq ? 96 : 32;
    const int N = isq ? 3072 : 1024;
    const int k0 = (t / ntiles) * 32, n0 = (t % ntiles) * 32;
    const int tx = threadIdx.x & 31, ty = threadIdx.x >> 5;   // 32 x 8
#pragma unroll
    for (int i = 0; i < 32; i += 8)
      tile[ty + i][tx] = W[(size_t)(k0 + ty + i) * N + n0 + tx];
    __syncthreads();
#pragma unroll
    for (int i = 0; i < 32; i += 8)
      Wt[(size_t)(n0 + ty + i) * 1024 + k0 + tx] = f2bf(tile[tx][ty + i]);
  } else {
    const int idx = (bid - 8192) * 256 + threadIdx.x;   // 65536 = 2048 * 32
    const int s = idx >> 5, i = idx & 31;
    float inv = exp2f(-13.287712379549449f * (float)i * (1.0f / 32.0f));  // 10000^(-i/32)
    float sn, cs;
    sincosf((float)s * inv, &sn, &cs);
    cost[idx] = cs;
    sint[idx] = sn;
  }
}

// ---------------------------------------------------------------- QKV GEMM fused
__global__ __launch_bounds__(256) void gemm_qkv_rope_kernel(const u16* __restrict__ A,
                                                            const u16* __restrict__ Bt,
                                                            const float* __restrict__ bias,
                                                            const float* __restrict__ cost,
                                                            const float* __restrict__ sint,
                                                            u16* __restrict__ qb,
                                                            u16* __restrict__ kb,
                                                            u16* __restrict__ vt) {
  __shared__ u16 As[128][64];
  __shared__ u16 Bs[128][64];
  const int bm = blockIdx.y, bn = blockIdx.x;
  const int tid = threadIdx.x;
  const int wave = tid >> 6, lane = tid & 63;
  const int wr = wave >> 1, wc = wave & 1;
  const int l15 = lane & 15, lhi = lane >> 4;
  f32x4 acc[4][4] = {};
  const int K = 1024;

  const size_t arow0 = (size_t)bm * 128, brow0 = (size_t)bn * 128;
  const int srow_in = lane >> 3;
  const int sslot   = (lane & 7) ^ srow_in;

  for (int k0 = 0; k0 < K; k0 += 64) {
#pragma unroll
    for (int i = 0; i < 4; i++) {
      const int r = wave * 32 + i * 8 + srow_in;
      GLOAD_LDS16(A  + (arow0 + r) * K + k0 + sslot * 8, &As[wave * 32 + i * 8][0]);
      GLOAD_LDS16(Bt + (brow0 + r) * K + k0 + sslot * 8, &Bs[wave * 32 + i * 8][0]);
    }
    __syncthreads();

    bf16x8 af[4][2], bfr[4][2];
#pragma unroll
    for (int m = 0; m < 4; m++) {
      const int r = wr * 64 + m * 16 + l15;
#pragma unroll
      for (int kk = 0; kk < 2; kk++)
        af[m][kk] = *(const bf16x8*)(&As[0][0] + r * 64 + (((kk * 4 + lhi) ^ (r & 7)) * 8));
    }
#pragma unroll
    for (int n = 0; n < 4; n++) {
      const int r = wc * 64 + n * 16 + l15;
#pragma unroll
      for (int kk = 0; kk < 2; kk++)
        bfr[n][kk] = *(const bf16x8*)(&Bs[0][0] + r * 64 + (((kk * 4 + lhi) ^ (r & 7)) * 8));
    }
#pragma unroll
    for (int m = 0; m < 4; m++)
#pragma unroll
      for (int n = 0; n < 4; n++) {
        acc[m][n] = __builtin_amdgcn_mfma_f32_16x16x32_bf16(af[m][0], bfr[n][0], acc[m][n], 0, 0, 0);
        acc[m][n] = __builtin_amdgcn_mfma_f32_16x16x32_bf16(af[m][1], bfr[n][1], acc[m][n], 0, 0, 0);
      }
    __syncthreads();
  }

  float bv[4];
#pragma unroll
  for (int n = 0; n < 4; n++) bv[n] = bias[bn * 128 + wc * 64 + n * 16 + l15];

  if (bn < 16) {   // ---- q or k: bias + RoPE ----
    const bool isq = bn < 8;
    u16* dst = isq ? qb : kb;
    const int hcol = bn * 2 + wc - (isq ? 0 : 16);   // head 0..15
    const float fold = isq ? QK_FOLD : 1.0f;
#pragma unroll
    for (int m = 0; m < 4; m++)
#pragma unroll
      for (int r = 0; r < 4; r++) {
        const int row = bm * 128 + wr * 64 + m * 16 + lhi * 4 + r;
        const int b = row >> 11, s = row & 2047;
        const float cs0 = cost[s * 32 + l15],      sn0 = sint[s * 32 + l15];
        const float cs1 = cost[s * 32 + 16 + l15], sn1 = sint[s * 32 + 16 + l15];
        const float q0 = acc[m][0][r] + bv[0], q1 = acc[m][2][r] + bv[2];
        const float q2 = acc[m][1][r] + bv[1], q3 = acc[m][3][r] + bv[3];
        u16* orow = dst + ((size_t)(b * 16 + hcol) * 2048 + s) * 64;
        orow[l15]      = f2bf((q0 * cs0 - q1 * sn0) * fold);
        orow[l15 + 32] = f2bf((q1 * cs0 + q0 * sn0) * fold);
        orow[l15 + 16] = f2bf((q2 * cs1 - q3 * sn1) * fold);
        orow[l15 + 48] = f2bf((q3 * cs1 + q2 * sn1) * fold);
      }
  } else {         // ---- v: bias + transpose to [bh][d][2048] ----
    const int hcol = bn * 2 + wc - 32;               // head 0..15
    const int b = bm >> 4;
#pragma unroll
    for (int n = 0; n < 4; n++) {
      const int d = n * 16 + l15;
      u16* dcol = vt + ((size_t)(b * 16 + hcol) * 64 + d) * 2048;
#pragma unroll
      for (int m = 0; m < 4; m++) {
        const int s = (bm * 128 + wr * 64 + m * 16 + lhi * 4) & 2047;
        uint2 w;
        w.x = (u32)f2bf(acc[m][n][0] + bv[n]) | ((u32)f2bf(acc[m][n][1] + bv[n]) << 16);
        w.y = (u32)f2bf(acc[m][n][2] + bv[n]) | ((u32)f2bf(acc[m][n][3] + bv[n]) << 16);
        *(uint2*)(dcol + s) = w;
      }
    }
  }
}

// ---------------------------------------------------------------- proj GEMM, 64x128 tile
__global__ __launch_bounds__(256) void gemm_bias_m64_kernel(const u16* __restrict__ A,
                                                            const u16* __restrict__ Bt,
                                                            const float* __restrict__ bias,
                                                            float* __restrict__ C,
                                                            int M, int N, int K) {
  __shared__ u16 As[64][64];
  __shared__ u16 Bs[128][64];
  const int bm = blockIdx.y, bn = blockIdx.x;
  const int tid = threadIdx.x;
  const int wave = tid >> 6, lane = tid & 63;
  const int wr = wave >> 1, wc = wave & 1;
  const int l15 = lane & 15, lhi = lane >> 4;
  f32x4 acc[2][4] = {};

  const size_t arow0 = (size_t)bm * 64, brow0 = (size_t)bn * 128;
  const int srow_in = lane >> 3;
  const int sslot   = (lane & 7) ^ srow_in;

  for (int k0 = 0; k0 < K; k0 += 64) {
#pragma unroll
    for (int i = 0; i < 2; i++) {   // A: 64 rows, 2 issues/wave
      const int r = wave * 16 + i * 8 + srow_in;
      GLOAD_LDS16(A + (arow0 + r) * K + k0 + sslot * 8, &As[wave * 16 + i * 8][0]);
    }
#pragma unroll
    for (int i = 0; i < 4; i++) {   // B: 128 rows, 4 issues/wave
      const int r = wave * 32 + i * 8 + srow_in;
      GLOAD_LDS16(Bt + (brow0 + r) * K + k0 + sslot * 8, &Bs[wave * 32 + i * 8][0]);
    }
    __syncthreads();

    bf16x8 af[2][2], bfr[4][2];
#pragma unroll
    for (int m = 0; m < 2; m++) {
      const int r = wr * 32 + m * 16 + l15;
#pragma unroll
      for (int kk = 0; kk < 2; kk++)
        af[m][kk] = *(const bf16x8*)(&As[0][0] + r * 64 + (((kk * 4 + lhi) ^ (r & 7)) * 8));
    }
#pragma unroll
    for (int n = 0; n < 4; n++) {
      const int r = wc * 64 + n * 16 + l15;
#pragma unroll
      for (int kk = 0; kk < 2; kk++)
        bfr[n][kk] = *(const bf16x8*)(&Bs[0][0] + r * 64 + (((kk * 4 + lhi) ^ (r & 7)) * 8));
    }
#pragma unroll
    for (int m = 0; m < 2; m++)
#pragma unroll
      for (int n = 0; n < 4; n++) {
        acc[m][n] = __builtin_amdgcn_mfma_f32_16x16x32_bf16(af[m][0], bfr[n][0], acc[m][n], 0, 0, 0);
        acc[m][n] = __builtin_amdgcn_mfma_f32_16x16x32_bf16(af[m][1], bfr[n][1], acc[m][n], 0, 0, 0);
      }
    __syncthreads();
  }
#pragma unroll
  for (int n = 0; n < 4; n++) {
    int col = bn * 128 + wc * 64 + n * 16 + l15;
    float bvv = bias[col];
#pragma unroll
    for (int m = 0; m < 2; m++)
#pragma unroll
      for (int r = 0; r < 4; r++) {
        int row = bm * 64 + wr * 32 + m * 16 + lhi * 4 + r;
        C[(size_t)row * N + col] = acc[m][n][r] + bvv;
      }
  }
}

// ---------------------------------------------------------------- flash attention
// R17: R13's validated structure with TWO 64-key sub-tiles per barrier pair
// (KVBLK=128, 16 barriers instead of 32). Each sub-tile is bit-identical to
// R13's [64][64] swizzled layout; kreg/vreg (2 each) are REUSED across
// sub-steps so register footprint matches R13: per sub-step = {issue next
// loads -> compute (covers latency) -> write regs to buf^1}. Same softmax
// (chain max + defer-max T13), same epilogue.
// WATCH: WRITE_SIZE must stay 8192 KB (spill detector); LDS 64 KB.
__global__ __launch_bounds__(256) void flash_attn_kernel(const u16* __restrict__ qg,
                                                         const u16* __restrict__ kg,
                                                         const u16* __restrict__ vg,
                                                         u16* __restrict__ og) {
  __shared__ u16 Ks[2][2][64][64];
  __shared__ u16 Vs[2][2][64][64];
  const int hw = blockIdx.x;
  const int lb = (hw & 7) * 64 + (hw >> 3);      // XCD swizzle: 4 bh per XCD
  const int qt = lb & 15, bh = lb >> 4;
  const int b = bh >> 4, h = bh & 15;
  const int tid = threadIdx.x, wave = tid >> 6, lane = tid & 63;
  const int l5 = lane & 31, hi = lane >> 5;

  const u16* qrow = qg + ((size_t)bh * 2048 + qt * 128 + wave * 32 + l5) * 64 + hi * 8;
  bf16x8 qf[4];
#pragma unroll
  for (int kc = 0; kc < 4; kc++) qf[kc] = *(const bf16x8*)(qrow + kc * 16);

  f32x16 o[2] = {};
  float m_run = -1e30f, l_run = 0.f;

  const u16* gK = kg + (size_t)bh * 2048 * 64;
  const u16* gV = vg + (size_t)bh * 64 * 2048;
  const int srow0 = tid >> 3, sc16 = tid & 7;
  int4 kreg[2], vreg[2];

  // prologue: stage key group 0 (subs 0 and 1) into buffer 0
#pragma unroll
  for (int sub = 0; sub < 2; sub++) {
#pragma unroll
    for (int i = 0; i < 2; i++) {
      int r = srow0 + i * 32;
      kreg[i] = *(const int4*)(gK + (size_t)(sub * 64 + r) * 64 + sc16 * 8);
      vreg[i] = *(const int4*)(gV + (size_t)r * 2048 + sub * 64 + sc16 * 8);
    }
#pragma unroll
    for (int i = 0; i < 2; i++) {
      int r = srow0 + i * 32;
      int byo = r * 128 + ((sc16 * 16) ^ ((r & 7) << 4));
      *(int4*)((char*)&Ks[0][sub][0][0] + byo) = kreg[i];
      *(int4*)((char*)&Vs[0][sub][0][0] + byo) = vreg[i];
    }
  }

#define SUB_STEP(SUB)                                                          \
  {                                                                            \
    if (g < 15) {                                                              \
      _Pragma("unroll")                                                        \
      for (int i = 0; i < 2; i++) {                                            \
        int r = srow0 + i * 32;                                                \
        kreg[i] = *(const int4*)(gK + ((size_t)(g + 1) * 128 + SUB * 64 + r) * 64 + sc16 * 8); \
        vreg[i] = *(const int4*)(gV + (size_t)r * 2048 + (g + 1) * 128 + SUB * 64 + sc16 * 8); \
      }                                                                        \
    }                                                                          \
    const char* KsB = (const char*)&Ks[cur][SUB][0][0];                        \
    const char* VsB = (const char*)&Vs[cur][SUB][0][0];                        \
    f32x16 sf[2];                                                              \
    _Pragma("unroll")                                                          \
    for (int k32 = 0; k32 < 2; k32++) {                                        \
      int r = k32 * 32 + l5;                                                   \
      const char* rowp = KsB + r * 128;                                        \
      int sw = (r & 7) << 4;                                                   \
      f32x16 s = {};                                                           \
      _Pragma("unroll")                                                        \
      for (int kc = 0; kc < 4; kc++) {                                         \
        bf16x8 kf = *(const bf16x8*)(rowp + ((kc * 32 + hi * 16) ^ sw));       \
        s = __builtin_amdgcn_mfma_f32_32x32x16_bf16(kf, qf[kc], s, 0, 0, 0);   \
      }                                                                        \
      sf[k32] = s;                                                             \
    }                                                                          \
    float pmax = sf[0][0];                                                     \
    _Pragma("unroll")                                                          \
    for (int r = 1; r < 16; r++) pmax = fmaxf(pmax, sf[0][r]);                 \
    _Pragma("unroll")                                                          \
    for (int r = 0; r < 16; r++) pmax = fmaxf(pmax, sf[1][r]);                 \
    pmax = fmaxf(pmax, __shfl_xor(pmax, 32));                                  \
    if (!__all(pmax - m_run <= 11.541560327111707f)) {                         \
      float mnew = fmaxf(m_run, pmax);                                         \
      float alpha = __builtin_amdgcn_exp2f(m_run - mnew);                      \
      m_run = mnew;                                                            \
      l_run *= alpha;                                                          \
      _Pragma("unroll")                                                        \
      for (int dc = 0; dc < 2; dc++)                                           \
        _Pragma("unroll")                                                      \
        for (int r = 0; r < 16; r++) o[dc][r] *= alpha;                        \
    }                                                                          \
    float rs = 0.f;                                                            \
    _Pragma("unroll")                                                          \
    for (int k32 = 0; k32 < 2; k32++)                                          \
      _Pragma("unroll")                                                        \
      for (int r = 0; r < 16; r++) {                                           \
        float p = __builtin_amdgcn_exp2f(sf[k32][r] - m_run);                  \
        sf[k32][r] = p;                                                        \
        rs += p;                                                               \
      }                                                                        \
    rs += __shfl_xor(rs, 32);                                                  \
    l_run += rs;                                                               \
    bf16x8 pf[4];                                                              \
    _Pragma("unroll")                                                          \
    for (int k32 = 0; k32 < 2; k32++) {                                        \
      u32 u[8];                                                                \
      _Pragma("unroll")                                                        \
      for (int m = 0; m < 8; m++) {                                            \
        u32 w;                                                                 \
        asm("v_cvt_pk_bf16_f32 %0, %1, %2" : "=v"(w) : "v"(sf[k32][2 * m]), "v"(sf[k32][2 * m + 1])); \
        u[m] = w;                                                              \
      }                                                                        \
      asm("v_permlane32_swap_b32 %0, %1" : "+v"(u[0]), "+v"(u[2]));            \
      asm("v_permlane32_swap_b32 %0, %1" : "+v"(u[1]), "+v"(u[3]));            \
      asm("v_permlane32_swap_b32 %0, %1" : "+v"(u[4]), "+v"(u[6]));            \
      asm("v_permlane32_swap_b32 %0, %1" : "+v"(u[5]), "+v"(u[7]));            \
      u32x4 w0 = {u[0], u[1], u[2], u[3]};                                     \
      u32x4 w1 = {u[4], u[5], u[6], u[7]};                                     \
      pf[k32 * 2]     = __builtin_bit_cast(bf16x8, w0);                        \
      pf[k32 * 2 + 1] = __builtin_bit_cast(bf16x8, w1);                        \
    }                                                                          \
    _Pragma("unroll")                                                          \
    for (int dc = 0; dc < 2; dc++) {                                           \
      int r = dc * 32 + l5;                                                    \
      const char* rowp = VsB + r * 128;                                        \
      int sw = (r & 7) << 4;                                                   \
      _Pragma("unroll")                                                        \
      for (int kc = 0; kc < 4; kc++) {                                         \
        bf16x8 vf = *(const bf16x8*)(rowp + ((kc * 32 + hi * 16) ^ sw));       \
        o[dc] = __builtin_amdgcn_mfma_f32_32x32x16_bf16(vf, pf[kc], o[dc], 0, 0, 0); \
      }                                                                        \
    }                                                                          \
    if (g < 15) {                                                              \
      _Pragma("unroll")                                                        \
      for (int i = 0; i < 2; i++) {                                            \
        int r = srow0 + i * 32;                                                \
        int byo = r * 128 + ((sc16 * 16) ^ ((r & 7) << 4));                    \
        *(int4*)((char*)&Ks[cur ^ 1][SUB][0][0] + byo) = kreg[i];              \
        *(int4*)((char*)&Vs[cur ^ 1][SUB][0][0] + byo) = vreg[i];              \
      }                                                                        \
    }                                                                          \
  }

  for (int g = 0; g < 16; g++) {
    const int cur = g & 1;
    __syncthreads();
    SUB_STEP(0);
    SUB_STEP(1);
  }
#undef SUB_STEP

  float rinv = 1.0f / l_run;
  int qglob = qt * 128 + wave * 32 + l5;
  u16* orow = og + ((size_t)b * 2048 + qglob) * 1024 + h * 64;
#pragma unroll
  for (int dc = 0; dc < 2; dc++)
#pragma unroll
    for (int m = 0; m < 4; m++) {
      int d0 = dc * 32 + m * 8 + hi * 4;
      float a0 = o[dc][4 * m + 0] * rinv, a1 = o[dc][4 * m + 1] * rinv;
      float a2 = o[dc][4 * m + 2] * rinv, a3 = o[dc][4 * m + 3] * rinv;
      uint2 w;
      w.x = (u32)f2bf(a0) | ((u32)f2bf(a1) << 16);
      w.y = (u32)f2bf(a2) | ((u32)f2bf(a3) << 16);
      *(uint2*)(orow + d0) = w;
    }
}

// ---------------------------------------------------------------- launch
extern "C" void kernel_launch(void* const* d_in, const int* in_sizes, int n_in,
                              void* d_out, int out_size, void* d_ws, size_t ws_size,
                              hipStream_t stream) {
  const float* x     = (const float*)d_in[0];
  const float* Wqkv  = (const float*)d_in[1];
  const float* bqkv  = (const float*)d_in[2];
  const float* Wproj = (const float*)d_in[3];
  const float* bproj = (const float*)d_in[4];
  float* out = (float*)d_out;

  // workspace layout (<= 96 MB)
  char* ws = (char*)d_ws;
  u16*   xb    = (u16*)ws;                                   // 8 MB  [4096][1024]
  u16*   wqkvt = xb + (size_t)4096 * 1024;                   // 6 MB  [3072][1024]
  u16*   wprot = wqkvt + (size_t)3072 * 1024;                // 2 MB  [1024][1024]
  float* cost  = (float*)(ws + (size_t)16 * 1024 * 1024);    // 256 KB [2048][32]
  float* sint  = cost + 2048 * 32;                           // 256 KB
  u16*   qb2   = (u16*)(ws + (size_t)64 * 1024 * 1024);      // 8 MB  [32][2048][64]
  u16*   kb2   = (u16*)(ws + (size_t)72 * 1024 * 1024);      // 8 MB
  u16*   vtw   = (u16*)(ws + (size_t)80 * 1024 * 1024);      // 8 MB  [32][64][2048]
  u16*   obw   = (u16*)(ws + (size_t)88 * 1024 * 1024);      // 8 MB  [4096][1024]

  prep_kernel<<<dim3(8448), dim3(256), 0, stream>>>(x, xb, Wqkv, wqkvt, Wproj, wprot, cost, sint);
  gemm_qkv_rope_kernel<<<dim3(24, 32), dim3(256), 0, stream>>>(xb, wqkvt, bqkv, cost, sint,
                                                               qb2, kb2, vtw);
  flash_attn_kernel<<<dim3(512), dim3(256), 0, stream>>>(qb2, kb2, vtw, obw);
  gemm_bias_m64_kernel<<<dim3(8, 64), dim3(256), 0, stream>>>(obw, wprot, bproj, out, 4096, 1024, 1024);
}

// Round 18
// 127.831 us; speedup vs baseline: 1.2943x; 1.0027x over previous
//
#include <hip/hip_runtime.h>

typedef unsigned short u16;
typedef unsigned int   u32;
typedef __bf16 bf16x8 __attribute__((ext_vector_type(8)));
typedef float  f32x4  __attribute__((ext_vector_type(4)));
typedef float  f32x16 __attribute__((ext_vector_type(16)));
typedef u32    u32x4  __attribute__((ext_vector_type(4)));

__device__ __forceinline__ u16 f2bf(float f) {
  u32 u = __builtin_bit_cast(u32, f);
  u += 0x7fffu + ((u >> 16) & 1u);   // RNE
  return (u16)(u >> 16);
}

#define GLOAD_LDS16(gptr, lptr)                                              \
  __builtin_amdgcn_global_load_lds(                                          \
      (const __attribute__((address_space(1))) void*)(gptr),                 \
      (__attribute__((address_space(3))) void*)(lptr), 16, 0, 0)

#define QK_FOLD 0.18033688011112042f   // 0.125 * log2(e): softmax in base-2

// ---------------------------------------------------------------- merged prep
__global__ __launch_bounds__(256) void prep_kernel(const float* __restrict__ x,
                                                   u16* __restrict__ xb,
                                                   const float* __restrict__ Wq,
                                                   u16* __restrict__ Wqt,
                                                   const float* __restrict__ Wp,
                                                   u16* __restrict__ Wpt,
                                                   float* __restrict__ cost,
                                                   float* __restrict__ sint) {
  __shared__ float tile[32][33];
  const int bid = blockIdx.x;
  if (bid < 4096) {
    const int i = bid * 256 + threadIdx.x;          // 1048576 = 4096*256 exact
    const float4 v = ((const float4*)x)[i];
    uint2 o;
    o.x = (u32)f2bf(v.x) | ((u32)f2bf(v.y) << 16);
    o.y = (u32)f2bf(v.z) | ((u32)f2bf(v.w) << 16);
    ((uint2*)xb)[i] = o;
  } else if (bid < 8192) {
    const bool isq = bid < 7168;
    const float* W = isq ? Wq : Wp;
    u16* Wt = isq ? Wqt : Wpt;
    const int t = isq ? (bid - 4096) : (bid - 7168);
    const int ntiles = isq ? 96 : 32;
    const int N = isq ? 3072 : 1024;
    const int k0 = (t / ntiles) * 32, n0 = (t % ntiles) * 32;
    const int tx = threadIdx.x & 31, ty = threadIdx.x >> 5;   // 32 x 8
#pragma unroll
    for (int i = 0; i < 32; i += 8)
      tile[ty + i][tx] = W[(size_t)(k0 + ty + i) * N + n0 + tx];
    __syncthreads();
#pragma unroll
    for (int i = 0; i < 32; i += 8)
      Wt[(size_t)(n0 + ty + i) * 1024 + k0 + tx] = f2bf(tile[tx][ty + i]);
  } else {
    const int idx = (bid - 8192) * 256 + threadIdx.x;   // 65536 = 2048 * 32
    const int s = idx >> 5, i = idx & 31;
    float inv = exp2f(-13.287712379549449f * (float)i * (1.0f / 32.0f));  // 10000^(-i/32)
    float sn, cs;
    sincosf((float)s * inv, &sn, &cs);
    cost[idx] = cs;
    sint[idx] = sn;
  }
}

// ---------------------------------------------------------------- QKV GEMM fused
__global__ __launch_bounds__(256) void gemm_qkv_rope_kernel(const u16* __restrict__ A,
                                                            const u16* __restrict__ Bt,
                                                            const float* __restrict__ bias,
                                                            const float* __restrict__ cost,
                                                            const float* __restrict__ sint,
                                                            u16* __restrict__ qb,
                                                            u16* __restrict__ kb,
                                                            u16* __restrict__ vt) {
  __shared__ u16 As[128][64];
  __shared__ u16 Bs[128][64];
  const int bm = blockIdx.y, bn = blockIdx.x;
  const int tid = threadIdx.x;
  const int wave = tid >> 6, lane = tid & 63;
  const int wr = wave >> 1, wc = wave & 1;
  const int l15 = lane & 15, lhi = lane >> 4;
  f32x4 acc[4][4] = {};
  const int K = 1024;

  const size_t arow0 = (size_t)bm * 128, brow0 = (size_t)bn * 128;
  const int srow_in = lane >> 3;
  const int sslot   = (lane & 7) ^ srow_in;

  for (int k0 = 0; k0 < K; k0 += 64) {
#pragma unroll
    for (int i = 0; i < 4; i++) {
      const int r = wave * 32 + i * 8 + srow_in;
      GLOAD_LDS16(A  + (arow0 + r) * K + k0 + sslot * 8, &As[wave * 32 + i * 8][0]);
      GLOAD_LDS16(Bt + (brow0 + r) * K + k0 + sslot * 8, &Bs[wave * 32 + i * 8][0]);
    }
    __syncthreads();

    bf16x8 af[4][2], bfr[4][2];
#pragma unroll
    for (int m = 0; m < 4; m++) {
      const int r = wr * 64 + m * 16 + l15;
#pragma unroll
      for (int kk = 0; kk < 2; kk++)
        af[m][kk] = *(const bf16x8*)(&As[0][0] + r * 64 + (((kk * 4 + lhi) ^ (r & 7)) * 8));
    }
#pragma unroll
    for (int n = 0; n < 4; n++) {
      const int r = wc * 64 + n * 16 + l15;
#pragma unroll
      for (int kk = 0; kk < 2; kk++)
        bfr[n][kk] = *(const bf16x8*)(&Bs[0][0] + r * 64 + (((kk * 4 + lhi) ^ (r & 7)) * 8));
    }
#pragma unroll
    for (int m = 0; m < 4; m++)
#pragma unroll
      for (int n = 0; n < 4; n++) {
        acc[m][n] = __builtin_amdgcn_mfma_f32_16x16x32_bf16(af[m][0], bfr[n][0], acc[m][n], 0, 0, 0);
        acc[m][n] = __builtin_amdgcn_mfma_f32_16x16x32_bf16(af[m][1], bfr[n][1], acc[m][n], 0, 0, 0);
      }
    __syncthreads();
  }

  float bv[4];
#pragma unroll
  for (int n = 0; n < 4; n++) bv[n] = bias[bn * 128 + wc * 64 + n * 16 + l15];

  if (bn < 16) {   // ---- q or k: bias + RoPE ----
    const bool isq = bn < 8;
    u16* dst = isq ? qb : kb;
    const int hcol = bn * 2 + wc - (isq ? 0 : 16);   // head 0..15
    const float fold = isq ? QK_FOLD : 1.0f;
#pragma unroll
    for (int m = 0; m < 4; m++)
#pragma unroll
      for (int r = 0; r < 4; r++) {
        const int row = bm * 128 + wr * 64 + m * 16 + lhi * 4 + r;
        const int b = row >> 11, s = row & 2047;
        const float cs0 = cost[s * 32 + l15],      sn0 = sint[s * 32 + l15];
        const float cs1 = cost[s * 32 + 16 + l15], sn1 = sint[s * 32 + 16 + l15];
        const float q0 = acc[m][0][r] + bv[0], q1 = acc[m][2][r] + bv[2];
        const float q2 = acc[m][1][r] + bv[1], q3 = acc[m][3][r] + bv[3];
        u16* orow = dst + ((size_t)(b * 16 + hcol) * 2048 + s) * 64;
        orow[l15]      = f2bf((q0 * cs0 - q1 * sn0) * fold);
        orow[l15 + 32] = f2bf((q1 * cs0 + q0 * sn0) * fold);
        orow[l15 + 16] = f2bf((q2 * cs1 - q3 * sn1) * fold);
        orow[l15 + 48] = f2bf((q3 * cs1 + q2 * sn1) * fold);
      }
  } else {         // ---- v: bias + transpose to [bh][d][2048] ----
    const int hcol = bn * 2 + wc - 32;               // head 0..15
    const int b = bm >> 4;
#pragma unroll
    for (int n = 0; n < 4; n++) {
      const int d = n * 16 + l15;
      u16* dcol = vt + ((size_t)(b * 16 + hcol) * 64 + d) * 2048;
#pragma unroll
      for (int m = 0; m < 4; m++) {
        const int s = (bm * 128 + wr * 64 + m * 16 + lhi * 4) & 2047;
        uint2 w;
        w.x = (u32)f2bf(acc[m][n][0] + bv[n]) | ((u32)f2bf(acc[m][n][1] + bv[n]) << 16);
        w.y = (u32)f2bf(acc[m][n][2] + bv[n]) | ((u32)f2bf(acc[m][n][3] + bv[n]) << 16);
        *(uint2*)(dcol + s) = w;
      }
    }
  }
}

// ---------------------------------------------------------------- proj GEMM, 64x128 tile
__global__ __launch_bounds__(256) void gemm_bias_m64_kernel(const u16* __restrict__ A,
                                                            const u16* __restrict__ Bt,
                                                            const float* __restrict__ bias,
                                                            float* __restrict__ C,
                                                            int M, int N, int K) {
  __shared__ u16 As[64][64];
  __shared__ u16 Bs[128][64];
  const int bm = blockIdx.y, bn = blockIdx.x;
  const int tid = threadIdx.x;
  const int wave = tid >> 6, lane = tid & 63;
  const int wr = wave >> 1, wc = wave & 1;
  const int l15 = lane & 15, lhi = lane >> 4;
  f32x4 acc[2][4] = {};

  const size_t arow0 = (size_t)bm * 64, brow0 = (size_t)bn * 128;
  const int srow_in = lane >> 3;
  const int sslot   = (lane & 7) ^ srow_in;

  for (int k0 = 0; k0 < K; k0 += 64) {
#pragma unroll
    for (int i = 0; i < 2; i++) {   // A: 64 rows, 2 issues/wave
      const int r = wave * 16 + i * 8 + srow_in;
      GLOAD_LDS16(A + (arow0 + r) * K + k0 + sslot * 8, &As[wave * 16 + i * 8][0]);
    }
#pragma unroll
    for (int i = 0; i < 4; i++) {   // B: 128 rows, 4 issues/wave
      const int r = wave * 32 + i * 8 + srow_in;
      GLOAD_LDS16(Bt + (brow0 + r) * K + k0 + sslot * 8, &Bs[wave * 32 + i * 8][0]);
    }
    __syncthreads();

    bf16x8 af[2][2], bfr[4][2];
#pragma unroll
    for (int m = 0; m < 2; m++) {
      const int r = wr * 32 + m * 16 + l15;
#pragma unroll
      for (int kk = 0; kk < 2; kk++)
        af[m][kk] = *(const bf16x8*)(&As[0][0] + r * 64 + (((kk * 4 + lhi) ^ (r & 7)) * 8));
    }
#pragma unroll
    for (int n = 0; n < 4; n++) {
      const int r = wc * 64 + n * 16 + l15;
#pragma unroll
      for (int kk = 0; kk < 2; kk++)
        bfr[n][kk] = *(const bf16x8*)(&Bs[0][0] + r * 64 + (((kk * 4 + lhi) ^ (r & 7)) * 8));
    }
#pragma unroll
    for (int m = 0; m < 2; m++)
#pragma unroll
      for (int n = 0; n < 4; n++) {
        acc[m][n] = __builtin_amdgcn_mfma_f32_16x16x32_bf16(af[m][0], bfr[n][0], acc[m][n], 0, 0, 0);
        acc[m][n] = __builtin_amdgcn_mfma_f32_16x16x32_bf16(af[m][1], bfr[n][1], acc[m][n], 0, 0, 0);
      }
    __syncthreads();
  }
#pragma unroll
  for (int n = 0; n < 4; n++) {
    int col = bn * 128 + wc * 64 + n * 16 + l15;
    float bvv = bias[col];
#pragma unroll
    for (int m = 0; m < 2; m++)
#pragma unroll
      for (int r = 0; r < 4; r++) {
        int row = bm * 64 + wr * 32 + m * 16 + lhi * 4 + r;
        C[(size_t)row * N + col] = acc[m][n][r] + bvv;
      }
  }
}

// ---------------------------------------------------------------- flash attention
// R18: R17 structure (KVBLK=128, 16 barriers, validated 62.5us) with ONE
// change: fragment-order LDS [dB][key'][8] / [kB][d'][8] with low-3-bit XOR
// on the middle index (key' = key ^ dB; d' = d ^ kB). Writes: 8 lanes per
// bank-quad with distinct addresses = same balance as the canonical
// lane-consecutive pattern (R4 measured 0 conflicts). Reads: permuted-lane-
// consecutive (XOR by <8 permutes within the 128B bank cycle) = conflict-free.
// Replaces the old byte-XOR layout whose reads were 4-way aliased (4.19M).
// WATCH: WRITE_SIZE must stay 8192 KB; conflicts should drop to ~0.
__global__ __launch_bounds__(256) void flash_attn_kernel(const u16* __restrict__ qg,
                                                         const u16* __restrict__ kg,
                                                         const u16* __restrict__ vg,
                                                         u16* __restrict__ og) {
  __shared__ u16 Ks[2][2][8][64][8];
  __shared__ u16 Vs[2][2][8][64][8];
  const int hw = blockIdx.x;
  const int lb = (hw & 7) * 64 + (hw >> 3);      // XCD swizzle: 4 bh per XCD
  const int qt = lb & 15, bh = lb >> 4;
  const int b = bh >> 4, h = bh & 15;
  const int tid = threadIdx.x, wave = tid >> 6, lane = tid & 63;
  const int l5 = lane & 31, hi = lane >> 5;

  const u16* qrow = qg + ((size_t)bh * 2048 + qt * 128 + wave * 32 + l5) * 64 + hi * 8;
  bf16x8 qf[4];
#pragma unroll
  for (int kc = 0; kc < 4; kc++) qf[kc] = *(const bf16x8*)(qrow + kc * 16);

  f32x16 o[2] = {};
  float m_run = -1e30f, l_run = 0.f;

  const u16* gK = kg + (size_t)bh * 2048 * 64;
  const u16* gV = vg + (size_t)bh * 64 * 2048;
  const int srow0 = tid >> 3, sc16 = tid & 7;
  int4 kreg[2], vreg[2];

  // prologue: stage key group 0 (subs 0 and 1) into buffer 0
#pragma unroll
  for (int sub = 0; sub < 2; sub++) {
#pragma unroll
    for (int i = 0; i < 2; i++) {
      int r = srow0 + i * 32;
      kreg[i] = *(const int4*)(gK + (size_t)(sub * 64 + r) * 64 + sc16 * 8);
      vreg[i] = *(const int4*)(gV + (size_t)r * 2048 + sub * 64 + sc16 * 8);
    }
#pragma unroll
    for (int i = 0; i < 2; i++) {
      int r = srow0 + i * 32;
      *(int4*)(&Ks[0][sub][sc16][r ^ sc16][0]) = kreg[i];
      *(int4*)(&Vs[0][sub][sc16][r ^ sc16][0]) = vreg[i];
    }
  }

#define SUB_STEP(SUB)                                                          \
  {                                                                            \
    if (g < 15) {                                                              \
      _Pragma("unroll")                                                        \
      for (int i = 0; i < 2; i++) {                                            \
        int r = srow0 + i * 32;                                                \
        kreg[i] = *(const int4*)(gK + ((size_t)(g + 1) * 128 + SUB * 64 + r) * 64 + sc16 * 8); \
        vreg[i] = *(const int4*)(gV + (size_t)r * 2048 + (g + 1) * 128 + SUB * 64 + sc16 * 8); \
      }                                                                        \
    }                                                                          \
    f32x16 sf[2];                                                              \
    _Pragma("unroll")                                                          \
    for (int k32 = 0; k32 < 2; k32++) {                                        \
      f32x16 s = {};                                                           \
      _Pragma("unroll")                                                        \
      for (int kc = 0; kc < 4; kc++) {                                         \
        const int dB = kc * 2 + hi;                                            \
        bf16x8 kf = *(const bf16x8*)(&Ks[cur][SUB][dB][(k32 * 32 + l5) ^ dB][0]); \
        s = __builtin_amdgcn_mfma_f32_32x32x16_bf16(kf, qf[kc], s, 0, 0, 0);   \
      }                                                                        \
      sf[k32] = s;                                                             \
    }                                                                          \
    float pmax = sf[0][0];                                                     \
    _Pragma("unroll")                                                          \
    for (int r = 1; r < 16; r++) pmax = fmaxf(pmax, sf[0][r]);                 \
    _Pragma("unroll")                                                          \
    for (int r = 0; r < 16; r++) pmax = fmaxf(pmax, sf[1][r]);                 \
    pmax = fmaxf(pmax, __shfl_xor(pmax, 32));                                  \
    if (!__all(pmax - m_run <= 11.541560327111707f)) {                         \
      float mnew = fmaxf(m_run, pmax);                                         \
      float alpha = __builtin_amdgcn_exp2f(m_run - mnew);                      \
      m_run = mnew;                                                            \
      l_run *= alpha;                                                          \
      _Pragma("unroll")                                                        \
      for (int dc = 0; dc < 2; dc++)                                           \
        _Pragma("unroll")                                                      \
        for (int r = 0; r < 16; r++) o[dc][r] *= alpha;                        \
    }                                                                          \
    float rs = 0.f;                                                            \
    _Pragma("unroll")                                                          \
    for (int k32 = 0; k32 < 2; k32++)                                          \
      _Pragma("unroll")                                                        \
      for (int r = 0; r < 16; r++) {                                           \
        float p = __builtin_amdgcn_exp2f(sf[k32][r] - m_run);                  \
        sf[k32][r] = p;                                                        \
        rs += p;                                                               \
      }                                                                        \
    rs += __shfl_xor(rs, 32);                                                  \
    l_run += rs;                                                               \
    bf16x8 pf[4];                                                              \
    _Pragma("unroll")                                                          \
    for (int k32 = 0; k32 < 2; k32++) {                                        \
      u32 u[8];                                                                \
      _Pragma("unroll")                                                        \
      for (int m = 0; m < 8; m++) {                                            \
        u32 w;                                                                 \
        asm("v_cvt_pk_bf16_f32 %0, %1, %2" : "=v"(w) : "v"(sf[k32][2 * m]), "v"(sf[k32][2 * m + 1])); \
        u[m] = w;                                                              \
      }                                                                        \
      asm("v_permlane32_swap_b32 %0, %1" : "+v"(u[0]), "+v"(u[2]));            \
      asm("v_permlane32_swap_b32 %0, %1" : "+v"(u[1]), "+v"(u[3]));            \
      asm("v_permlane32_swap_b32 %0, %1" : "+v"(u[4]), "+v"(u[6]));            \
      asm("v_permlane32_swap_b32 %0, %1" : "+v"(u[5]), "+v"(u[7]));            \
      u32x4 w0 = {u[0], u[1], u[2], u[3]};                                     \
      u32x4 w1 = {u[4], u[5], u[6], u[7]};                                     \
      pf[k32 * 2]     = __builtin_bit_cast(bf16x8, w0);                        \
      pf[k32 * 2 + 1] = __builtin_bit_cast(bf16x8, w1);                        \
    }                                                                          \
    _Pragma("unroll")                                                          \
    for (int dc = 0; dc < 2; dc++) {                                           \
      _Pragma("unroll")                                                        \
      for (int kc = 0; kc < 4; kc++) {                                         \
        const int kB = kc * 2 + hi;                                            \
        bf16x8 vf = *(const bf16x8*)(&Vs[cur][SUB][kB][(dc * 32 + l5) ^ kB][0]); \
        o[dc] = __builtin_amdgcn_mfma_f32_32x32x16_bf16(vf, pf[kc], o[dc], 0, 0, 0); \
      }                                                                        \
    }                                                                          \
    if (g < 15) {                                                              \
      _Pragma("unroll")                                                        \
      for (int i = 0; i < 2; i++) {                                            \
        int r = srow0 + i * 32;                                                \
        *(int4*)(&Ks[cur ^ 1][SUB][sc16][r ^ sc16][0]) = kreg[i];              \
        *(int4*)(&Vs[cur ^ 1][SUB][sc16][r ^ sc16][0]) = vreg[i];              \
      }                                                                        \
    }                                                                          \
  }

  for (int g = 0; g < 16; g++) {
    const int cur = g & 1;
    __syncthreads();
    SUB_STEP(0);
    SUB_STEP(1);
  }
#undef SUB_STEP

  float rinv = 1.0f / l_run;
  int qglob = qt * 128 + wave * 32 + l5;
  u16* orow = og + ((size_t)b * 2048 + qglob) * 1024 + h * 64;
#pragma unroll
  for (int dc = 0; dc < 2; dc++)
#pragma unroll
    for (int m = 0; m < 4; m++) {
      int d0 = dc * 32 + m * 8 + hi * 4;
      float a0 = o[dc][4 * m + 0] * rinv, a1 = o[dc][4 * m + 1] * rinv;
      float a2 = o[dc][4 * m + 2] * rinv, a3 = o[dc][4 * m + 3] * rinv;
      uint2 w;
      w.x = (u32)f2bf(a0) | ((u32)f2bf(a1) << 16);
      w.y = (u32)f2bf(a2) | ((u32)f2bf(a3) << 16);
      *(uint2*)(orow + d0) = w;
    }
}

// ---------------------------------------------------------------- launch
extern "C" void kernel_launch(void* const* d_in, const int* in_sizes, int n_in,
                              void* d_out, int out_size, void* d_ws, size_t ws_size,
                              hipStream_t stream) {
  const float* x     = (const float*)d_in[0];
  const float* Wqkv  = (const float*)d_in[1];
  const float* bqkv  = (const float*)d_in[2];
  const float* Wproj = (const float*)d_in[3];
  const float* bproj = (const float*)d_in[4];
  float* out = (float*)d_out;

  // workspace layout (<= 96 MB)
  char* ws = (char*)d_ws;
  u16*   xb    = (u16*)ws;                                   // 8 MB  [4096][1024]
  u16*   wqkvt = xb + (size_t)4096 * 1024;                   // 6 MB  [3072][1024]
  u16*   wprot = wqkvt + (size_t)3072 * 1024;                // 2 MB  [1024][1024]
  float* cost  = (float*)(ws + (size_t)16 * 1024 * 1024);    // 256 KB [2048][32]
  float* sint  = cost + 2048 * 32;                           // 256 KB
  u16*   qb2   = (u16*)(ws + (size_t)64 * 1024 * 1024);      // 8 MB  [32][2048][64]
  u16*   kb2   = (u16*)(ws + (size_t)72 * 1024 * 1024);      // 8 MB
  u16*   vtw   = (u16*)(ws + (size_t)80 * 1024 * 1024);      // 8 MB  [32][64][2048]
  u16*   obw   = (u16*)(ws + (size_t)88 * 1024 * 1024);      // 8 MB  [4096][1024]

  prep_kernel<<<dim3(8448), dim3(256), 0, stream>>>(x, xb, Wqkv, wqkvt, Wproj, wprot, cost, sint);
  gemm_qkv_rope_kernel<<<dim3(24, 32), dim3(256), 0, stream>>>(xb, wqkvt, bqkv, cost, sint,
                                                               qb2, kb2, vtw);
  flash_attn_kernel<<<dim3(512), dim3(256), 0, stream>>>(qb2, kb2, vtw, obw);
  gemm_bias_m64_kernel<<<dim3(8, 64), dim3(256), 0, stream>>>(obw, wprot, bproj, out, 4096, 1024, 1024);
}